// Round 1
// baseline (108.192 us; speedup 1.0000x reference)
//
#include <hip/hip_runtime.h>
#include <math.h>

// Problem constants
#define B_   4
#define DM   64   // d_model
#define DS   16   // d_state
#define HH_  32
#define WW_  32
#define HW_  1024 // 32*32
#define NV   9    // (2*1+1)^2 shifts

// d_out layout: y_out (B,9,64,32,32) = 2359296 floats, then s_next (B,9,64,16,32,32)
#define Y_SIZE   2359296
// ws layout (floats): delta[B][64][1024], B_val[B][16][1024], C_val[B][16][1024]
#define WS_DELTA 0
#define WS_BV    (B_*DM*HW_)            // 262144
#define WS_CV    (WS_BV + B_*DS*HW_)    // 327680

// ---------------------------------------------------------------------------
// Kernel 1: the three circular 3x3 convolutions.
// Grid: B * 24 blocks (24 groups of 4 output channels: 16 delta-groups,
// 4 B_val-groups, 4 C_val-groups). Block: 1024 threads = one pixel each.
// u-plane for each input channel staged in LDS; 4 weights per tap read as a
// single broadcast float4 from LDS.
// ---------------------------------------------------------------------------
__global__ __launch_bounds__(1024) void conv_kernel(
    const float* __restrict__ u,
    const float* __restrict__ Wd,
    const float* __restrict__ bd,
    const float* __restrict__ Wb,
    const float* __restrict__ Wc,
    const float* __restrict__ dtp,
    float* __restrict__ ws)
{
    __shared__ float su[HW_];
    __shared__ float sw[DM * 9 * 4];   // [ci][tap][j]  (j = 4 output channels)

    const int bid = blockIdx.x;
    const int b   = bid / 24;
    const int g   = bid % 24;
    const int co0 = g * 4;

    const float* Wsrc;
    int cbase, mode;
    if (co0 < 64)      { Wsrc = Wd; cbase = co0;      mode = 0; }
    else if (co0 < 80) { Wsrc = Wb; cbase = co0 - 64; mode = 1; }
    else               { Wsrc = Wc; cbase = co0 - 80; mode = 2; }

    const int tid = threadIdx.x;

    // stage weights: sw[(ci*9+tap)*4 + j] = Wsrc[(cbase+j)*576 + ci*9+tap]
    for (int i = tid; i < DM * 9 * 4; i += 1024) {
        const int j  = i & 3;
        const int ct = i >> 2;          // ci*9 + tap
        sw[i] = Wsrc[(cbase + j) * 576 + ct];
    }

    const int h = tid >> 5;
    const int w = tid & 31;

    float acc0 = 0.f, acc1 = 0.f, acc2 = 0.f, acc3 = 0.f;
    const float* ub = u + (size_t)b * DM * HW_;

    for (int ci = 0; ci < DM; ++ci) {
        __syncthreads();                 // also covers the weight staging (ci==0)
        su[tid] = ub[ci * HW_ + tid];
        __syncthreads();
        #pragma unroll
        for (int kh = 0; kh < 3; ++kh) {
            const int hh = (h + kh + 31) & 31;   // (h + kh - 1) mod 32
            #pragma unroll
            for (int kw = 0; kw < 3; ++kw) {
                const int ww = (w + kw + 31) & 31;
                const float v = su[(hh << 5) | ww];
                const float4 wv = *(const float4*)&sw[(ci * 9 + kh * 3 + kw) * 4];
                acc0 = fmaf(v, wv.x, acc0);
                acc1 = fmaf(v, wv.y, acc1);
                acc2 = fmaf(v, wv.z, acc2);
                acc3 = fmaf(v, wv.w, acc3);
            }
        }
    }

    float acc[4] = {acc0, acc1, acc2, acc3};
    if (mode == 0) {
        const float dt = dtp[0];
        #pragma unroll
        for (int j = 0; j < 4; ++j) {
            const float x  = acc[j] + bd[cbase + j] + dt;
            // softplus = max(x,0) + log1p(exp(-|x|))  (matches jax.nn.softplus)
            const float sp = fmaxf(x, 0.f) + log1pf(expf(-fabsf(x)));
            ws[WS_DELTA + ((size_t)b * DM + cbase + j) * HW_ + tid] = sp;
        }
    } else if (mode == 1) {
        #pragma unroll
        for (int j = 0; j < 4; ++j)
            ws[WS_BV + ((size_t)b * DS + cbase + j) * HW_ + tid] = acc[j];
    } else {
        #pragma unroll
        for (int j = 0; j < 4; ++j)
            ws[WS_CV + ((size_t)b * DS + cbase + j) * HW_ + tid] = acc[j];
    }
}

// ---------------------------------------------------------------------------
// Kernel 2: state update + output. One thread per (b,c,h,w).
// Reads s_prev once (151 MB), writes s_next once (151 MB) + y_out (9.4 MB).
// ---------------------------------------------------------------------------
__global__ __launch_bounds__(256) void scan_kernel(
    const float* __restrict__ u,
    const float* __restrict__ s_prev,
    const float* __restrict__ logA,
    const float* __restrict__ Dv,
    const float* __restrict__ ws,
    float* __restrict__ out)
{
    const int t = blockIdx.x * 256 + threadIdx.x;   // 0 .. B*DM*HW-1 (262144)
    const int w = t & 31;
    const int h = (t >> 5) & 31;
    const int c = (t >> 10) & 63;    // uniform within a block
    const int b = t >> 16;           // uniform within a block
    const int hw = (h << 5) | w;

    const float u_val = u[t];                 // u layout == t linear layout
    const float delta = ws[WS_DELTA + t];

    float Abar[DS], bu[DS], Cr[DS];
    #pragma unroll
    for (int n = 0; n < DS; ++n) {
        const float A  = -expf(logA[c * DS + n]);     // uniform -> scalar load
        const float e  = expf(delta * A);
        Abar[n] = e;
        const float Bb = (e - 1.0f) / A * ws[WS_BV + ((size_t)b * DS + n) * HW_ + hw];
        bu[n]  = Bb * u_val;
        Cr[n]  = ws[WS_CV + ((size_t)b * DS + n) * HW_ + hw];
    }
    const float Du = u_val * Dv[c];

    float* __restrict__ y_out = out;
    float* __restrict__ s_out = out + Y_SIZE;

    #pragma unroll
    for (int v = 0; v < NV; ++v) {
        const int sx = v / 3 - 1;                 // SHIFTS order: x outer, y inner
        const int sy = v % 3 - 1;
        const int hs = (h + sy) & 31;
        const int ws2 = (w + sx) & 31;
        const size_t base = (((size_t)(b * NV + v) * DM + c) * DS) * HW_;
        const float* __restrict__ sp = s_prev + base;
        float* __restrict__ so = s_out + base;
        const int shw = (hs << 5) | ws2;

        float acc = 0.f;
        #pragma unroll
        for (int n = 0; n < DS; ++n) {
            const float s = fmaf(Abar[n], sp[n * HW_ + shw], bu[n]);
            so[n * HW_ + hw] = s;
            acc = fmaf(s, Cr[n], acc);
        }
        y_out[((size_t)(b * NV + v) * DM + c) * HW_ + hw] = acc + Du;
    }
}

extern "C" void kernel_launch(void* const* d_in, const int* in_sizes, int n_in,
                              void* d_out, int out_size, void* d_ws, size_t ws_size,
                              hipStream_t stream) {
    const float* u      = (const float*)d_in[0];
    const float* s_prev = (const float*)d_in[1];
    const float* Wd     = (const float*)d_in[2];
    const float* bd     = (const float*)d_in[3];
    const float* Wb     = (const float*)d_in[4];
    const float* Wc     = (const float*)d_in[5];
    const float* logA   = (const float*)d_in[6];
    const float* Dv     = (const float*)d_in[7];
    const float* dtp    = (const float*)d_in[8];
    float* out = (float*)d_out;
    float* ws  = (float*)d_ws;

    conv_kernel<<<B_ * 24, 1024, 0, stream>>>(u, Wd, bd, Wb, Wc, dtp, ws);
    scan_kernel<<<(B_ * DM * HW_) / 256, 256, 0, stream>>>(u, s_prev, logA, Dv, ws, out);
}